// Round 9
// baseline (38.629 us; speedup 1.0000x reference)
//
#include <hip/hip_runtime.h>
#include <math.h>

#define NB 4
#define FRAMES 400
#define NBINS 129
#define HOP 240
#define T_LEN (FRAMES * HOP)   // 96000
#define KLEN 256               // FIR length = 2*(NBINS-1)

#define REC_C { const float cn_ = fmaf(a2, cm, -cm1); cm1 = cm; cm = cn_; }
#define REC_S { const float sn_ = fmaf(a2, sm, -sm1); sm1 = sm; sm = sn_; }

// ---------------------------------------------------------------------------
// FUSED kernel. Block (bs, b) produces outputs [start,end) of batch b, which
// all share interpolation rows (f, fh). Phase A: wave 0 computes FIR row f,
// wave 1 row fh, via the R5-proven mod-4 fold (lane n -> taps n, n+64, n+128,
// n+192; Chebyshev recurrences; HW trig in revolutions). All phase-A LDS is
// wave-private (DS ops are in-order within a wave -> no barriers). Phase B:
// R6-proven fir inner loop; k-taps come from LDS b128 broadcasts (no SMEM ->
// no lgkmcnt(0) drains), x from LDS b64 reads.
// Segments: bs=0:[0,120) f=0;  bs=1..399:[240bs-120,240bs+120) f=bs-1;
//           bs=400:[95880,96000) f=fh=399.
// ---------------------------------------------------------------------------
__global__ __launch_bounds__(128) void ltv_fused(const float* __restrict__ ex,
                                                 const float* __restrict__ log_mag,
                                                 float* __restrict__ out) {
    const int b    = blockIdx.y;
    const int bs   = blockIdx.x;          // 0..400
    const int tid  = threadIdx.x;         // 0..127
    const int wv   = tid >> 6;            // wave 0 -> row f, wave 1 -> row fh
    const int lane = tid & 63;

    const int start = (bs == 0) ? 0 : 240 * bs - 120;
    const int end   = min(T_LEN, 240 * bs + 120);
    const int f     = (bs == 0) ? 0 : bs - 1;
    const int fr    = min(f + wv, FRAMES - 1);   // this wave's row index

    __shared__ __align__(16) float  lm01[2][132];   // staged log_mag rows (pad->16B stride)
    __shared__ __align__(16) float  g2[2][128];     // per-wave Xf[k]/128
    __shared__ __align__(16) float2 crci2[2][128];  // per-wave (wC[k], wS[k])
    __shared__ __align__(16) float  kerL[256];      // row f   (windowed FIR)
    __shared__ __align__(16) float  kerH[256];      // row fh
    __shared__ __align__(16) float  xs[512];        // x[start-255 .. start+240]

    // ---- stage x window (both waves cooperatively)
    const float* xb = ex + b * T_LEN;
    for (int i = tid; i < 496; i += 128) {
        const int t = start - 255 + i;
        xs[i] = (t >= 0 && t < T_LEN) ? xb[t] : 0.0f;
    }

    // ---- stage this wave's log_mag row (wave-local)
    const float* lmg = log_mag + (b * FRAMES + fr) * NBINS;
    float* lmW = lm01[wv];
    for (int i = lane; i < NBINS; i += 64) lmW[i] = lmg[i];

    const float rev_n = (float)lane * (1.0f / 256.0f);
    const float ca = __builtin_amdgcn_cosf(rev_n);   // cos(2*pi*n/256)
    const float sa = __builtin_amdgcn_sinf(rev_n);
    const float a2  = 2.0f * ca;
    const float sgn = (lane & 1) ? -1.0f : 1.0f;     // (-1)^n

    float* gW = g2[wv];
    float2* crciW = crci2[wv];

    const float f0s  = lmW[0];
    const float f128 = lmW[128];

    // ---- Phase A, loop 1: Xf[n], Xf[n+64] via mod-4 phase fold
    {
        const float4* lmW4 = (const float4*)lmW;
        float cm1 = ca, cm = 1.0f, sm1 = -sa, sm = 0.0f;
        float U = 0.0f, V = 0.0f;
#pragma unroll
        for (int u = 0; u < 32; ++u) {
            const float4 f4 = lmW4[u];
            U = fmaf(f4.x, cm, U); V = fmaf(f4.x, cm, V);  REC_C; REC_S;   // m=4u
            U = fmaf(f4.y, cm, U); V = fmaf(-f4.y, sm, V); REC_C; REC_S;   // m=4u+1
            U = fmaf(f4.z, cm, U); V = fmaf(-f4.z, cm, V); REC_C; REC_S;   // m=4u+2
            U = fmaf(f4.w, cm, U); V = fmaf(f4.w, sm, V);  REC_C; REC_S;   // m=4u+3
        }
        const float base0 = -f0s + sgn * f128;
        gW[lane]      = (base0 + 2.0f * U) * (1.0f / 128.0f);
        gW[lane + 64] = (base0 + 2.0f * V) * (1.0f / 128.0f);
    }

    // ---- Phase A, loop 2: mp[n], mp[n+64]; then modulated spectrum
    {
        const float4* g4p = (const float4*)gW;
        float cm1 = ca, cm = 1.0f, sm1 = -sa, sm = 0.0f;
        float U = 0.0f, V = 0.0f;
#pragma unroll
        for (int u = 0; u < 32; ++u) {
            const float4 gv = g4p[u];
            U = fmaf(gv.x, sm, U); V = fmaf(gv.x, sm, V);  REC_C; REC_S;   // k=4u
            U = fmaf(gv.y, sm, U); V = fmaf(gv.y, cm, V);  REC_C; REC_S;   // k=4u+1
            U = fmaf(gv.z, sm, U); V = fmaf(-gv.z, sm, V); REC_C; REC_S;   // k=4u+2
            U = fmaf(gv.w, sm, U); V = fmaf(-gv.w, cm, V); REC_C; REC_S;   // k=4u+3
        }
        const float mp0 = -U, mp1 = -V;
        const float lmn0 = lmW[lane];
        const float lmn1 = lmW[lane + 64];
        const float e0 = __builtin_amdgcn_exp2f(lmn0 * 1.4426950408889634f);
        const float e1 = __builtin_amdgcn_exp2f(lmn1 * 1.4426950408889634f);
        float r0 = mp0 * 0.15915494309189535f; r0 -= floorf(r0);
        float r1 = mp1 * 0.15915494309189535f; r1 -= floorf(r1);
        const float w0 = (lane == 0) ? 1.0f : 2.0f;
        crciW[lane]      = make_float2(w0 * e0 * __builtin_amdgcn_cosf(r0),
                                       w0 * e0 * __builtin_amdgcn_sinf(r0));
        crciW[lane + 64] = make_float2(2.0f * e1 * __builtin_amdgcn_cosf(r1),
                                       2.0f * e1 * __builtin_amdgcn_sinf(r1));
    }

    // ---- Phase A, loop 3: W0..W3, X1, X3 -> four windowed taps into LDS
    {
        const float4* cc4 = (const float4*)crciW;
        float cm1 = ca, cm = 1.0f, sm1 = -sa, sm = 0.0f;
        float W0 = 0.0f, W1 = 0.0f, W2 = 0.0f, W3 = 0.0f, X1 = 0.0f, X3 = 0.0f;
#pragma unroll
        for (int u = 0; u < 32; ++u) {
            const float4 q1 = cc4[2 * u];       // C'[4u], S'[4u], C'[4u+1], S'[4u+1]
            const float4 q2 = cc4[2 * u + 1];   // C'[4u+2], S'[4u+2], C'[4u+3], S'[4u+3]
            W0 = fmaf(q1.x, cm, W0); W0 = fmaf(-q1.y, sm, W0); REC_C; REC_S;   // k=4u
            W1 = fmaf(q1.z, cm, W1); W1 = fmaf(-q1.w, sm, W1);
            X1 = fmaf(q1.z, sm, X1); X1 = fmaf(q1.w, cm, X1);  REC_C; REC_S;   // k=4u+1
            W2 = fmaf(q2.x, cm, W2); W2 = fmaf(-q2.y, sm, W2); REC_C; REC_S;   // k=4u+2
            W3 = fmaf(q2.z, cm, W3); W3 = fmaf(-q2.w, sm, W3);
            X3 = fmaf(q2.z, sm, X3); X3 = fmaf(q2.w, cm, X3);  REC_C; REC_S;   // k=4u+3
        }
        const float e128 = __builtin_amdgcn_exp2f(f128 * 1.4426950408889634f);
        const float base0 = sgn * e128;
        const float s = 1.0f / 256.0f;
        float* kerW = wv ? kerH : kerL;
        kerW[lane]       = (W0 + W1 + W2 + W3 + base0) * s;                       // hann=1
        kerW[lane + 64]  = (W0 - X1 - W2 + X3 + base0) * s;                       // hann=1
        kerW[lane + 128] = (W0 - W1 + W2 - W3 + base0) * s * (0.5f + 0.5f * ca);  // tail
        kerW[lane + 192] = (W0 + X1 - W2 - X3 + base0) * s * (0.5f - 0.5f * sa);  // tail
    }

    __syncthreads();   // kerL/kerH/xs now visible to all

    // ---- Phase B: fir for 2 adjacent outputs per thread (R6-proven)
    const int te = start + 2 * tid;
    if (te >= end) return;

    float se = ((float)te + 0.5f) * (1.0f / HOP) - 0.5f;
    se = fminf(fmaxf(se, 0.0f), (float)(FRAMES - 1));
    float so = ((float)te + 1.5f) * (1.0f / HOP) - 0.5f;
    so = fminf(fmaxf(so, 0.0f), (float)(FRAMES - 1));
    const float we = se - (float)f;
    const float wo = so - (float)f;

    const float4* kL4 = (const float4*)kerL;   // wave-uniform -> LDS broadcast
    const float4* kH4 = (const float4*)kerH;

    const int base = 2 * tid;                  // xs index of x[te] is base+255
    float carry = xs[base + 256];              // x[te+1]
    float aeL = 0.0f, aeH = 0.0f, aoL = 0.0f, aoH = 0.0f;
#pragma unroll 4
    for (int u = 0; u < 64; ++u) {
        const float2 v1 = *(const float2*)&xs[base + 254 - 4 * u];  // x[te-4u-1], x[te-4u]
        const float2 v0 = *(const float2*)&xs[base + 252 - 4 * u];  // x[te-4u-3], x[te-4u-2]
        const float4 kl4 = kL4[u];
        const float4 kh4 = kH4[u];
        // tap j=4u   : e->v1.y  o->carry
        aeL = fmaf(v1.y,  kl4.x, aeL); aeH = fmaf(v1.y,  kh4.x, aeH);
        aoL = fmaf(carry, kl4.x, aoL); aoH = fmaf(carry, kh4.x, aoH);
        // tap j=4u+1 : e->v1.x  o->v1.y
        aeL = fmaf(v1.x,  kl4.y, aeL); aeH = fmaf(v1.x,  kh4.y, aeH);
        aoL = fmaf(v1.y,  kl4.y, aoL); aoH = fmaf(v1.y,  kh4.y, aoH);
        // tap j=4u+2 : e->v0.y  o->v1.x
        aeL = fmaf(v0.y,  kl4.z, aeL); aeH = fmaf(v0.y,  kh4.z, aeH);
        aoL = fmaf(v1.x,  kl4.z, aoL); aoH = fmaf(v1.x,  kh4.z, aoH);
        // tap j=4u+3 : e->v0.x  o->v0.y
        aeL = fmaf(v0.x,  kl4.w, aeL); aeH = fmaf(v0.x,  kh4.w, aeH);
        aoL = fmaf(v0.y,  kl4.w, aoL); aoH = fmaf(v0.y,  kh4.w, aoH);
        carry = v0.x;
    }

    const float y0 = aeL + we * (aeH - aeL);
    const float y1 = aoL + wo * (aoH - aoL);
    *(float2*)(out + b * T_LEN + te) = make_float2(y0, y1);  // te even -> aligned
}

// ---------------------------------------------------------------------------
extern "C" void kernel_launch(void* const* d_in, const int* in_sizes, int n_in,
                              void* d_out, int out_size, void* d_ws, size_t ws_size,
                              hipStream_t stream) {
    const float* ex      = (const float*)d_in[0];
    const float* log_mag = (const float*)d_in[1];
    float* out = (float*)d_out;

    dim3 grid(401, NB);   // 401 frame-aligned segments x 4 batches, one dispatch
    ltv_fused<<<grid, 128, 0, stream>>>(ex, log_mag, out);
}

// Round 10
// 24.344 us; speedup vs baseline: 1.5868x; 1.5868x over previous
//
#include <hip/hip_runtime.h>
#include <math.h>

#define NB 4
#define FRAMES 400
#define NBINS 129
#define HOP 240
#define T_LEN (FRAMES * HOP)   // 96000
#define KLEN 256               // FIR length = 2*(NBINS-1)

#define REC_C { const float cn_ = fmaf(a2, cm, -cm1); cm1 = cm; cm = cn_; }
#define REC_S { const float sn_ = fmaf(a2, sm, -sm1); sm1 = sm; sm = sn_; }

// ---------------------------------------------------------------------------
// Kernel 1 (R6-proven, best measured gen): per (b,frame) windowed
// minimum-phase FIR (256 taps), 128 threads. Parity split: thread n computes
// ker[n] and ker[n+128]. float4 LDS broadcasts; Chebyshev recurrences;
// HW trig/exp (v_sin/v_cos take REVOLUTIONS; n/256 rev is exact).
// ---------------------------------------------------------------------------
__global__ __launch_bounds__(128) void gen_fir(const float* __restrict__ log_mag,
                                               float* __restrict__ kern) {
    const int bf = blockIdx.x;   // 0..NB*FRAMES-1
    const int n  = threadIdx.x;  // 0..127

    __shared__ __align__(16) float  full[132];   // lm[0..128]
    __shared__ __align__(16) float  g[128];      // Xf[k]/128
    __shared__ __align__(16) float2 crci[128];   // (wC[k], wS[k]); w=1 at k=0 else 2

    const float* lm = log_mag + bf * NBINS;
    full[n] = lm[n];
    if (n == 0) full[128] = lm[128];

    const float rev_n = (float)n * (1.0f / 256.0f);
    const float ca = __builtin_amdgcn_cosf(rev_n);   // cos(2*pi*n/256)
    const float sa = __builtin_amdgcn_sinf(rev_n);
    const float a2  = 2.0f * ca;
    const float sgn = (n & 1) ? -1.0f : 1.0f;        // (-1)^n
    __syncthreads();

    const float full0   = full[0];
    const float full128 = full[128];

    // ---- Xf[n] = 2*sum_{m=0..127} full[m] cos(mna) - full[0] + sgn*full[128]
    {
        const float4* f4p = (const float4*)full;
        float cm1 = ca, cm = 1.0f, acc = 0.0f;       // c_{-1}=cos(-a), c_0=1
#pragma unroll 8
        for (int u = 0; u < 32; ++u) {
            const float4 f4 = f4p[u];
            acc = fmaf(f4.x, cm, acc); REC_C;
            acc = fmaf(f4.y, cm, acc); REC_C;
            acc = fmaf(f4.z, cm, acc); REC_C;
            acc = fmaf(f4.w, cm, acc); REC_C;
        }
        const float Xf = 2.0f * acc - full0 + sgn * full128;
        g[n] = Xf * (1.0f / 128.0f);
    }
    __syncthreads();

    // ---- mp[n] = -sum_{k=0..127} g[k] sin(kna)   (k=0 term is 0)
    {
        const float4* g4p = (const float4*)g;
        float sm1 = -sa, sm = 0.0f, acc = 0.0f;      // s_{-1}=sin(-a), s_0=0
#pragma unroll 8
        for (int u = 0; u < 32; ++u) {
            const float4 gv = g4p[u];
            acc = fmaf(gv.x, sm, acc); REC_S;
            acc = fmaf(gv.y, sm, acc); REC_S;
            acc = fmaf(gv.z, sm, acc); REC_S;
            acc = fmaf(gv.w, sm, acc); REC_S;
        }
        const float mp = -acc;
        const float e  = __builtin_amdgcn_exp2f(full[n] * 1.4426950408889634f);
        float rev = mp * 0.15915494309189535f;       // mp / (2*pi)
        rev = rev - floorf(rev);                     // v_fract reduction
        const float smp  = __builtin_amdgcn_sinf(rev);
        const float cmp_ = __builtin_amdgcn_cosf(rev);
        const float sc = (n == 0) ? 1.0f : 2.0f;
        crci[n] = make_float2(sc * e * cmp_, sc * e * smp);
    }
    __syncthreads();

    // ---- ker[n]     = (accE + accO + sgn*e128)/256          (hann = 1)
    //      ker[n+128] = (accE - accO + sgn*e128)/256*(0.5+0.5ca)
    {
        const float e128 = __builtin_amdgcn_exp2f(full128 * 1.4426950408889634f);
        const float4* cc4 = (const float4*)crci;
        float cm1 = ca, cm = 1.0f;     // k=0
        float sm1 = -sa, sm = 0.0f;
        float accE = 0.0f, accO = 0.0f;
#pragma unroll 8
        for (int u = 0; u < 64; ++u) {
            const float4 q = cc4[u];   // C'[2u], S'[2u], C'[2u+1], S'[2u+1]
            accE = fmaf(q.x, cm, accE); accE = fmaf(-q.y, sm, accE);
            REC_C; REC_S;
            accO = fmaf(q.z, cm, accO); accO = fmaf(-q.w, sm, accO);
            REC_C; REC_S;
        }
        const float base = sgn * e128;
        const float s = 1.0f / 256.0f;
        kern[bf * KLEN + n]       = (accE + accO + base) * s;
        kern[bf * KLEN + n + 128] = (accE - accO + base) * s * (0.5f + 0.5f * ca);
    }
}

// ---------------------------------------------------------------------------
// Kernel 2 (R3-proven, best measured fir): time-varying FIR. 256 threads,
// each computes 2 ADJACENT outputs (te=t0+2i, te+1). Frame boundaries sit
// between odd->even t, so a pair always shares lo -> no divergence. Kernel
// pair interleaved as float2 so one ds_read_b128 fetches 2 taps of both
// kernels; x via one b64 + register carry. 2-way max LDS aliasing (free).
// ---------------------------------------------------------------------------
__global__ __launch_bounds__(256) void fir_apply(const float* __restrict__ ex,
                                                 const float* __restrict__ kern,
                                                 float* __restrict__ out) {
    const int b   = blockIdx.y;
    const int t0  = blockIdx.x * 512;
    const int tid = threadIdx.x;

    __shared__ __align__(16) float  xs[768];        // x[t0-255 .. t0+255]
    __shared__ __align__(16) float2 kp[4][258];     // (kerLo[j], kerHi[j]) per q; +2 pad

    for (int i = tid; i < 768; i += 256) {
        const int t = t0 - 255 + i;
        xs[i] = (t >= 0 && t < T_LEN) ? ex[b * T_LEN + t] : 0.0f;
    }

    // frames needed by this block: f0 .. f0+3 (clamped)
    float src0 = ((float)t0 + 0.5f) * (1.0f / HOP) - 0.5f;
    src0 = fminf(fmaxf(src0, 0.0f), (float)(FRAMES - 1));
    const int f0 = (int)src0;
    const float* kb = kern + b * FRAMES * KLEN;
    for (int i = tid; i < 4 * KLEN; i += 256) {
        const int q = i >> 8;
        const int j = i & 255;
        const int fl = min(f0 + q,     FRAMES - 1);
        const int fh = min(f0 + q + 1, FRAMES - 1);
        kp[q][j] = make_float2(kb[fl * KLEN + j], kb[fh * KLEN + j]);
    }
    __syncthreads();

    const int te = t0 + 2 * tid;
    float se = ((float)te + 0.5f) * (1.0f / HOP) - 0.5f;
    se = fminf(fmaxf(se, 0.0f), (float)(FRAMES - 1));
    float so = ((float)te + 1.5f) * (1.0f / HOP) - 0.5f;
    so = fminf(fmaxf(so, 0.0f), (float)(FRAMES - 1));
    const int   lo = (int)se;           // == lo(te+1), boundary-safe by parity
    const float we = se - (float)lo;
    const float wo = so - (float)lo;

    const float4* kq4 = (const float4*)&kp[lo - f0][0];   // (kL[2u],kH[2u],kL[2u+1],kH[2u+1])

    const int base = 2 * tid;           // xs index of x[te] is base+255
    float carry = xs[base + 256];       // x[te+1]
    float aeL = 0.0f, aeH = 0.0f, aoL = 0.0f, aoH = 0.0f;
#pragma unroll 8
    for (int u = 0; u < 128; ++u) {
        const float2 v  = *(const float2*)&xs[base + 254 - 2 * u];  // (x[te-2u-1], x[te-2u])
        const float4 k4 = kq4[u];
        aeL = fmaf(v.y,   k4.x, aeL);  aeH = fmaf(v.y,   k4.y, aeH);   // out e, j=2u
        aoL = fmaf(carry, k4.x, aoL);  aoH = fmaf(carry, k4.y, aoH);   // out o, j=2u
        aeL = fmaf(v.x,   k4.z, aeL);  aeH = fmaf(v.x,   k4.w, aeH);   // out e, j=2u+1
        aoL = fmaf(v.y,   k4.z, aoL);  aoH = fmaf(v.y,   k4.w, aoH);   // out o, j=2u+1
        carry = v.x;
    }

    if (te < T_LEN)     out[b * T_LEN + te]     = (1.0f - we) * aeL + we * aeH;
    if (te + 1 < T_LEN) out[b * T_LEN + te + 1] = (1.0f - wo) * aoL + wo * aoH;
}

// ---------------------------------------------------------------------------
extern "C" void kernel_launch(void* const* d_in, const int* in_sizes, int n_in,
                              void* d_out, int out_size, void* d_ws, size_t ws_size,
                              hipStream_t stream) {
    const float* ex      = (const float*)d_in[0];
    const float* log_mag = (const float*)d_in[1];
    float* kern = (float*)d_ws;          // NB*FRAMES*KLEN floats = 1.6 MB
    float* out  = (float*)d_out;

    gen_fir<<<NB * FRAMES, 128, 0, stream>>>(log_mag, kern);

    dim3 grid((T_LEN + 511) / 512, NB);
    fir_apply<<<grid, 256, 0, stream>>>(ex, kern, out);
}